// Round 4
// baseline (369.640 us; speedup 1.0000x reference)
//
#include <hip/hip_runtime.h>

#define EPS 1e-6f
#define LN2F 0.69314718055994530942f

typedef float f32x4 __attribute__((ext_vector_type(4)));

// ----------------------------------------------------------------------------
// per-element: wbce term into `sum`, correctness bit into `nibs` at `bit`.
// ----------------------------------------------------------------------------
#define ONEB(pc, tc, wc, bit) {                                  \
    const bool  tb  = (tc) != 0.0f;  /* y_true is exactly 0/1 */ \
    const float sel = tb ? (pc) : 1.0f - (pc);                   \
    sum = fmaf((wc), __log2f(sel + EPS), sum);                   \
    nibs |= (unsigned)(((pc) > 0.5f) == tb) << (bit); }

// phase A: tight nibble per chunk q (bits 4q..4q+3)
#define CHUNK8(P, T, W, q) {                 \
    ONEB(P.x, T.x, W.x, 4*(q)+0)             \
    ONEB(P.y, T.y, W.y, 4*(q)+1)             \
    ONEB(P.z, T.z, W.z, 4*(q)+2)             \
    ONEB(P.w, T.w, W.w, 4*(q)+3) }

// fallback kernel: byte-per-chunk nibble (bits 8q..8q+3)
#define CHUNK_FB(P, T, W, q) {               \
    ONEB(P.x, T.x, W.x, 8*(q)+0)             \
    ONEB(P.y, T.y, W.y, 8*(q)+1)             \
    ONEB(P.z, T.z, W.z, 8*(q)+2)             \
    ONEB(P.w, T.w, W.w, 8*(q)+3) }

// issue one 16B coalesced load via raw asm: payload register is PINNED
// (allocator cannot sink/shrink it), issue order is program order.
#define GLOAD(dst, base)       asm volatile("global_load_dwordx4 %0, %1, off"             : "=v"(dst) : "v"(base))
#define GLOADO(dst, base, off) asm volatile("global_load_dwordx4 %0, %1, off offset:" #off : "=v"(dst) : "v"(base))

// counted wait: oldest (outstanding - N) vmem ops complete. sched_barrier
// stops hipcc hoisting the (register-only) consumers above the wait (rule #18).
#define VMWAIT(N) { asm volatile("s_waitcnt vmcnt(" #N ")" ::: "memory"); \
                    __builtin_amdgcn_sched_barrier(0); }

// ============================================================================
// Phase A: streaming with GUARANTEED deep memory concurrency (compiler taken
// out of the loop). 2048 blocks x 256 thr = 8192 waves, 2 tiles of 2048
// elements per wave. Per tile: 24 asm global_load_dwordx4 issued back-to-back
// (24KB/wave in flight), consumed chunk-by-chunk under counted vmcnt
// (21,18,...,0) so in-flight depth stays 24->3 during compute instead of the
// compiler's ~4-8 with drain-to-0 (VGPR=32/64 in rounds 0-3 proved the
// allocator kept sinking the loads; delivered BW pinned at 3.1 TB/s).
// ============================================================================
__global__ __launch_bounds__(256, 4) void phaseA_kernel(
        const float* __restrict__ yp, const float* __restrict__ yt,
        const float* __restrict__ dw,
        unsigned* __restrict__ masks,         // one uint per 32 elements
        float* __restrict__ wv_wbce,          // one partial per wave (8192)
        long tiles_total) {                   // tiles of 2048 elements
    const int lane = threadIdx.x & 63;
    const int wave = threadIdx.x >> 6;
    const long wgid = (long)blockIdx.x * 4 + wave;
    const long nwv  = (long)gridDim.x * 4;

    __shared__ unsigned nibbuf[256];          // wave-private 64-dword segments

    float sum = 0.0f;                         // raw sum of w * log2(sel + eps)

    for (long t = wgid; t < tiles_total; t += nwv) {
        const long base = t * 2048 + lane * 4;
        // two bases per stream: offset immediate is 13-bit (<4096B), chunk
        // stride is 1024B, chunks 4-7 sit at +4096B.
        const float* pa = yp + base;  const float* pb = pa + 1024;
        const float* ta = yt + base;  const float* tb = ta + 1024;
        const float* wa = dw + base;  const float* wb = wa + 1024;

        f32x4 p0, p1, p2, p3, p4, p5, p6, p7;
        f32x4 t0, t1, t2, t3, t4, t5, t6, t7;
        f32x4 w0, w1, w2, w3, w4, w5, w6, w7;

        // 24 loads, issue order = (p,t,w) per chunk, chunks 0..7.
        GLOAD (p0, pa);        GLOAD (t0, ta);        GLOAD (w0, wa);
        GLOADO(p1, pa, 1024);  GLOADO(t1, ta, 1024);  GLOADO(w1, wa, 1024);
        GLOADO(p2, pa, 2048);  GLOADO(t2, ta, 2048);  GLOADO(w2, wa, 2048);
        GLOADO(p3, pa, 3072);  GLOADO(t3, ta, 3072);  GLOADO(w3, wa, 3072);
        GLOAD (p4, pb);        GLOAD (t4, tb);        GLOAD (w4, wb);
        GLOADO(p5, pb, 1024);  GLOADO(t5, tb, 1024);  GLOADO(w5, wb, 1024);
        GLOADO(p6, pb, 2048);  GLOADO(t6, tb, 2048);  GLOADO(w6, wb, 2048);
        GLOADO(p7, pb, 3072);  GLOADO(t7, tb, 3072);  GLOADO(w7, wb, 3072);

        unsigned nibs = 0;                    // nibble q = correctness of chunk q
        // counted waits: before chunk q need oldest 3(q+1) loads done (the
        // <=1 outstanding masks-store from the previous tile was issued
        // before these loads and is absorbed by the same counts).
        VMWAIT(21) CHUNK8(p0, t0, w0, 0)
        VMWAIT(18) CHUNK8(p1, t1, w1, 1)
        VMWAIT(15) CHUNK8(p2, t2, w2, 2)
        VMWAIT(12) CHUNK8(p3, t3, w3, 3)
        VMWAIT(9)  CHUNK8(p4, t4, w4, 4)
        VMWAIT(6)  CHUNK8(p5, t5, w5, 5)
        VMWAIT(3)  CHUNK8(p6, t6, w6, 6)
        VMWAIT(0)  CHUNK8(p7, t7, w7, 7)

        // wave-private transpose: 1 dword write + 2 b128 reads (2-way banked
        // -> free per m136). Lane j gathers nibble (j>>3) of the 8 dwords
        // written by lanes (j&7)*8..+7 -> 32 bits covering elements
        // [t*2048 + 32j, +32) in sequence order.
        nibbuf[wave * 64 + lane] = nibs;
        asm volatile("s_waitcnt lgkmcnt(0)" ::: "memory");
        const uint4 da = *(const uint4*)&nibbuf[wave * 64 + (lane & 7) * 8];
        const uint4 db = *(const uint4*)&nibbuf[wave * 64 + (lane & 7) * 8 + 4];
        const int qs = (lane >> 3) * 4;       // nibble-selecting shift
        const unsigned m = ((da.x >> qs) & 0xFu)
                         | (((da.y >> qs) & 0xFu) << 4)
                         | (((da.z >> qs) & 0xFu) << 8)
                         | (((da.w >> qs) & 0xFu) << 12)
                         | (((db.x >> qs) & 0xFu) << 16)
                         | (((db.y >> qs) & 0xFu) << 20)
                         | (((db.z >> qs) & 0xFu) << 24)
                         | (((db.w >> qs) & 0xFu) << 28);
        masks[t * 64 + lane] = m;             // 256B/wave contiguous store
    }

    // one butterfly per wave for the whole kernel (amortized to ~0)
    #pragma unroll
    for (int off = 32; off; off >>= 1) sum += __shfl_down(sum, off);
    if (lane == 0) wv_wbce[wgid] = sum;
}

// ============================================================================
// Phase B: per-row max streak from masks. Row = 4KB of bits; lane reads one
// aligned uint64 (64 contiguous elements), 64-bit doubling ladder, 6-step
// ordered shuffle combine. 256 blocks x 4 waves.
// ============================================================================
__global__ __launch_bounds__(256, 4) void phaseB_kernel(
        const unsigned* __restrict__ masks,
        int* __restrict__ wv_streak, long rows) {
    const int lane = threadIdx.x & 63;
    const int wave = threadIdx.x >> 6;
    const long wgid = (long)blockIdx.x * 4 + wave;
    const long nwv  = (long)gridDim.x * 4;

    int acc = 0;
    for (long r = wgid; r < rows; r += nwv) {
        const unsigned long long m =
            *(const unsigned long long*)(masks + r * 128 + lane * 2);
        int pre, suf, mx;
        if (~m == 0ULL) {
            pre = suf = mx = 64;
        } else {
            pre = __builtin_ctzll(~m);            // leading-run (bit0 = first elem)
            suf = __builtin_clzll(~m);            // trailing-run (top bits)
            const unsigned long long pp1 = m;
            const unsigned long long pp2 = pp1 & (pp1 << 1);
            const unsigned long long pp4 = pp2 & (pp2 << 2);
            const unsigned long long pp8 = pp4 & (pp4 << 4);
            const unsigned long long pp16 = pp8 & (pp8 << 8);
            const unsigned long long pp32 = pp16 & (pp16 << 16);
            unsigned long long z; int len;
            if (pp32)      { z = pp32; len = 32; }
            else if (pp16) { z = pp16; len = 16; }
            else if (pp8)  { z = pp8;  len = 8; }
            else if (pp4)  { z = pp4;  len = 4; }
            else if (pp2)  { z = pp2;  len = 2; }
            else           { z = pp1;  len = 1; }
            { const unsigned long long q = (z << 16) & pp16; if (q) { z = q; len += 16; } }
            { const unsigned long long q = (z << 8)  & pp8;  if (q) { z = q; len += 8; } }
            { const unsigned long long q = (z << 4)  & pp4;  if (q) { z = q; len += 4; } }
            { const unsigned long long q = (z << 2)  & pp2;  if (q) { z = q; len += 2; } }
            { const unsigned long long q = (z << 1)  & pp1;  if (q) { z = q; len += 1; } }
            mx = m ? len : 0;
        }

        int alen = 64;
        #pragma unroll
        for (int off = 1; off < 64; off <<= 1) {
            const int bpre = __shfl_down(pre, off);
            const int bsuf = __shfl_down(suf, off);
            const int bmx  = __shfl_down(mx,  off);
            const int npre = (pre == alen) ? (alen + bpre) : pre;
            const int nsuf = (bsuf == alen) ? (alen + suf) : bsuf;
            mx  = max(max(mx, bmx), suf + bpre);
            pre = npre; suf = nsuf; alen <<= 1;
        }
        if (lane == 0) acc += mx;             // row max-streak
    }
    if (lane == 0) wv_streak[wgid] = acc;
}

// ============================================================================
// Finalize: sum 8192 wbce partials (double) + 1024 streak partials.
// ============================================================================
__global__ __launch_bounds__(1024) void finalize_kernel(
        const float* __restrict__ wv_wbce, int nA,
        const int* __restrict__ wv_streak, int nB,
        long long total_elems, float* __restrict__ out) {
    double s = 0.0;
    long long st = 0;
    for (int i = threadIdx.x; i < nA; i += 1024) s  += (double)wv_wbce[i];
    for (int i = threadIdx.x; i < nB; i += 1024) st += (long long)wv_streak[i];
    __shared__ double sd[1024];
    __shared__ long long sl[1024];
    sd[threadIdx.x] = s; sl[threadIdx.x] = st;
    __syncthreads();
    for (int o = 512; o; o >>= 1) {
        if (threadIdx.x < o) {
            sd[threadIdx.x] += sd[threadIdx.x + o];
            sl[threadIdx.x] += sl[threadIdx.x + o];
        }
        __syncthreads();
    }
    if (threadIdx.x == 0) {
        const double total = (double)total_elems;
        const double wbce = -LN2F * sd[0] / total;
        const double cwl  = 1.0 - (double)sl[0] / total;
        out[0] = (float)(0.5 * wbce + 0.5 * cwl);
    }
}

// ============================================================================
// Fallback (ws too small): round-0 proven single-pass kernel.
// ============================================================================
struct RunStats { int len, pre, suf, mx; };
__device__ inline RunStats rcombine(const RunStats& a, const RunStats& b) {
    RunStats r;
    r.len = a.len + b.len;
    r.pre = (a.pre == a.len) ? (a.len + b.pre) : a.pre;
    r.suf = (b.suf == b.len) ? (b.len + a.suf) : b.suf;
    r.mx  = max(max(a.mx, b.mx), a.suf + b.pre);
    return r;
}

__global__ __launch_bounds__(256) void fb_row_kernel(
        const float* __restrict__ yp, const float* __restrict__ yt,
        const float* __restrict__ dw,
        float* __restrict__ row_wbce, int* __restrict__ row_streak) {
    const int row  = blockIdx.x;
    const int lane = threadIdx.x & 63;
    const int wave = threadIdx.x >> 6;
    const long base = (long)row * 4096 + wave * 1024 + lane * 4;
    const float4* pp = (const float4*)(yp + base);
    const float4* tp = (const float4*)(yt + base);
    const float4* wp = (const float4*)(dw + base);

    float sum = 0.0f;
    unsigned nibs = 0;
    #pragma unroll
    for (int q = 0; q < 4; ++q) {
        const float4 P = pp[q * 64];
        const float4 T = tp[q * 64];
        const float4 W = wp[q * 64];
        CHUNK_FB(P, T, W, q)
    }
    __shared__ unsigned nibbuf[256];
    nibbuf[wave * 64 + lane] = nibs;
    __syncthreads();
    const uint4 d = *(const uint4*)&nibbuf[wave * 64 + 4 * (lane & 15)];
    const int qs = (lane >> 4) * 8;
    const unsigned mask = ((d.x >> qs) & 0xFu) | (((d.y >> qs) & 0xFu) << 4)
                        | (((d.z >> qs) & 0xFu) << 8) | (((d.w >> qs) & 0xFu) << 12);
    const int pre = __builtin_ctz(~mask);
    const int suf = __builtin_clz(~(mask << 16));
    int mx;
    {
        const unsigned p1 = mask, p2 = p1 & (p1 << 1), p4 = p2 & (p2 << 2), p8 = p4 & (p4 << 4);
        unsigned z; int len;
        if (p8) { z = p8; len = 8; } else if (p4) { z = p4; len = 4; }
        else if (p2) { z = p2; len = 2; } else { z = p1; len = 1; }
        { const unsigned q2 = (z << 8) & p8; if (q2) { z = q2; len += 8; } }
        { const unsigned q2 = (z << 4) & p4; if (q2) { z = q2; len += 4; } }
        { const unsigned q2 = (z << 2) & p2; if (q2) { z = q2; len += 2; } }
        { const unsigned q2 = (z << 1) & p1; if (q2) { z = q2; len += 1; } }
        mx = mask ? len : 0;
    }
    #pragma unroll
    for (int off = 32; off; off >>= 1) sum += __shfl_down(sum, off);
    int packed = pre | (suf << 10) | (mx << 20);
    int alen = 16;
    #pragma unroll
    for (int off = 1; off < 32; off <<= 1) {
        const int o = __shfl_down(packed, off);
        const int apre = packed & 1023, asuf = (packed >> 10) & 1023, amx = packed >> 20;
        const int bpre = o & 1023, bsuf = (o >> 10) & 1023, bmx = o >> 20;
        packed = ((apre == alen) ? (alen + bpre) : apre)
               | (((bsuf == alen) ? (alen + asuf) : bsuf) << 10)
               | (max(max(amx, bmx), asuf + bpre) << 20);
        alen <<= 1;
    }
    RunStats g;
    {
        const int o = __shfl_down(packed, 32);
        const int apre = packed & 1023, asuf = (packed >> 10) & 1023, amx = packed >> 20;
        const int bpre = o & 1023, bsuf = (o >> 10) & 1023, bmx = o >> 20;
        g.len = 1024;
        g.pre = (apre == 512) ? (512 + bpre) : apre;
        g.suf = (bsuf == 512) ? (512 + asuf) : bsuf;
        g.mx  = max(max(amx, bmx), asuf + bpre);
    }
    __shared__ RunStats sstat[4];
    __shared__ float ssum[4];
    if (lane == 0) { sstat[wave] = g; ssum[wave] = sum; }
    __syncthreads();
    if (threadIdx.x == 0) {
        RunStats r = rcombine(rcombine(sstat[0], sstat[1]), rcombine(sstat[2], sstat[3]));
        row_wbce[row]   = -LN2F * (ssum[0] + ssum[1] + ssum[2] + ssum[3]);
        row_streak[row] = r.mx;
    }
}

__global__ __launch_bounds__(1024) void fb_finalize_kernel(
        const float* __restrict__ row_wbce, const int* __restrict__ row_streak,
        int rows, float* __restrict__ out) {
    double s = 0.0; long long st = 0;
    for (int i = threadIdx.x; i < rows; i += 1024) {
        s += (double)row_wbce[i]; st += (long long)row_streak[i];
    }
    __shared__ double sd[1024];
    __shared__ long long sl[1024];
    sd[threadIdx.x] = s; sl[threadIdx.x] = st;
    __syncthreads();
    for (int o = 512; o; o >>= 1) {
        if (threadIdx.x < o) { sd[threadIdx.x] += sd[threadIdx.x + o]; sl[threadIdx.x] += sl[threadIdx.x + o]; }
        __syncthreads();
    }
    if (threadIdx.x == 0) {
        const double total = (double)rows * 4096.0;
        out[0] = (float)(0.5 * (sd[0] / total) + 0.5 * (1.0 - (double)sl[0] / total));
    }
}

extern "C" void kernel_launch(void* const* d_in, const int* in_sizes, int n_in,
                              void* d_out, int out_size, void* d_ws, size_t ws_size,
                              hipStream_t stream) {
    const float* yp = (const float*)d_in[0];
    const float* yt = (const float*)d_in[1];
    const float* dw = (const float*)d_in[2];
    float* out = (float*)d_out;

    const long rows = in_sizes[0] / 4096;             // 8192
    const long long total = (long long)rows * 4096;

    const size_t mask_bytes = (size_t)rows * 512;     // rows*128 uints
    const size_t off_wbce   = mask_bytes;             // 8192 floats
    const size_t off_streak = off_wbce + 8192 * sizeof(float);
    const size_t need       = off_streak + 1024 * sizeof(int);

    if (ws_size >= need) {
        unsigned* masks  = (unsigned*)d_ws;
        float* wv_wbce   = (float*)((char*)d_ws + off_wbce);
        int*   wv_streak = (int*)((char*)d_ws + off_streak);
        const long tiles_total = total / 2048;        // 2048-element tiles

        phaseA_kernel<<<2048, 256, 0, stream>>>(yp, yt, dw, masks, wv_wbce, tiles_total);
        phaseB_kernel<<<256, 256, 0, stream>>>(masks, wv_streak, rows);
        finalize_kernel<<<1, 1024, 0, stream>>>(wv_wbce, 8192, wv_streak, 1024, total, out);
    } else {
        float* row_wbce   = (float*)d_ws;
        int*   row_streak = (int*)((char*)d_ws + (size_t)rows * sizeof(float));
        fb_row_kernel<<<(int)rows, 256, 0, stream>>>(yp, yt, dw, row_wbce, row_streak);
        fb_finalize_kernel<<<1, 1024, 0, stream>>>(row_wbce, row_streak, (int)rows, out);
    }
}

// Round 6
// 361.881 us; speedup vs baseline: 1.0214x; 1.0214x over previous
//
#include <hip/hip_runtime.h>

#define EPS 1e-6f
#define LN2F 0.69314718055994530942f

// ----------------------------------------------------------------------------
// per-element: wbce term into `sum`, correctness bit into `nibs` at `bit`.
// ----------------------------------------------------------------------------
#define ONEB(pc, tc, wc, bit) {                                  \
    const bool  tb  = (tc) != 0.0f;  /* y_true is exactly 0/1 */ \
    const float sel = tb ? (pc) : 1.0f - (pc);                   \
    sum = fmaf((wc), __log2f(sel + EPS), sum);                   \
    nibs |= (unsigned)(((pc) > 0.5f) == tb) << (bit); }

// byte-spaced nibble per chunk q (bits 8q..8q+3) — round-2 proven layout
#define CHUNK_FB(P, T, W, q) {               \
    ONEB(P.x, T.x, W.x, 8*(q)+0)             \
    ONEB(P.y, T.y, W.y, 8*(q)+1)             \
    ONEB(P.z, T.z, W.z, 8*(q)+2)             \
    ONEB(P.w, T.w, W.w, 8*(q)+3) }

// counted wait on outstanding VMEM ops (global_load_lds counts in vmcnt).
#define VMWAIT(N) { asm volatile("s_waitcnt vmcnt(" #N ")" ::: "memory"); \
                    __builtin_amdgcn_sched_barrier(0); }

// global -> LDS direct DMA, 16B/lane: LDS dst = wave-uniform base + lane*16,
// global src = per-lane address. ZERO VGPR payload -> depth is free.
__device__ __forceinline__ void gload_lds16(const float* g, float* l) {
    __builtin_amdgcn_global_load_lds(
        (const __attribute__((address_space(1))) void*)g,
        (__attribute__((address_space(3)))       void*)l, 16, 0, 0);
}

// ============================================================================
// Phase A: streaming with REGISTER-FREE guaranteed memory depth.
// 4096 blocks x 128 thr = 8192 waves; each wave owns 4 tiles of 1024 elems.
// Tile staging: 12 x global_load_lds(16B-wide) into a 12KB LDS buffer
// (3 streams x 4KB), double-buffered. Steady state keeps the NEXT tile's 12
// loads (12KB/wave) in flight across the current tile's compute via
// VMWAIT(12) — vmcnt never drains to 0 until the wave's last tile. Rounds
// 0-4 proved the register allocator silently collapses register-payload
// depth (VGPR stuck at 32-64); LDS-destination loads cannot be collapsed.
// Bit plumbing (nibble layout, transpose, ushort masks) is the round-2
// proven version verbatim; per-tile mask footprint = 128B -> 4MB total.
// ============================================================================
__global__ __launch_bounds__(128) void phaseA_kernel(
        const float* __restrict__ yp, const float* __restrict__ yt,
        const float* __restrict__ dw,
        unsigned short* __restrict__ masks,   // one ushort per 16 elements
        float* __restrict__ wv_wbce,          // one partial per wave (8192)
        long tiles_total) {                   // tiles of 1024 elements
    const int lane = threadIdx.x & 63;
    const int wave = threadIdx.x >> 6;
    const long wgid = (long)blockIdx.x * 2 + wave;
    const long nwv  = (long)gridDim.x * 2;

    // [wave][parity][stream][1024 floats] = 48KB; + transpose scratch.
    __shared__ __align__(16) float sbuf[2][2][3][1024];
    __shared__ unsigned nibbuf[128];          // 64 dwords per wave

    float sum = 0.0f;                         // raw sum of w * log2(sel + eps)

    // issue the 12 staging loads for tile t into parity par (12KB/wave).
    auto ISSUE = [&](long t, int par) {
        const float* gp = yp + t * 1024 + lane * 4;
        const float* gt = yt + t * 1024 + lane * 4;
        const float* gw = dw + t * 1024 + lane * 4;
        #pragma unroll
        for (int c = 0; c < 4; ++c) {
            gload_lds16(gp + c * 256, &sbuf[wave][par][0][c * 256]);
            gload_lds16(gt + c * 256, &sbuf[wave][par][1][c * 256]);
            gload_lds16(gw + c * 256, &sbuf[wave][par][2][c * 256]);
        }
    };

    long t  = wgid;
    int par = 0;
    if (t < tiles_total) ISSUE(t, 0);

    for (; t < tiles_total; t += nwv, par ^= 1) {
        const long tn = t + nwv;
        if (tn < tiles_total) {
            ISSUE(tn, par ^ 1);               // next tile: 12 loads in flight
            VMWAIT(12)                        // current tile's 12 complete
                                              // (also absorbs prior ushort
                                              // store); next 12 outstanding
        } else {
            VMWAIT(0)                         // wave's final tile: drain once
        }

        const float* pb = &sbuf[wave][par][0][0];
        const float* tb = &sbuf[wave][par][1][0];
        const float* wb = &sbuf[wave][par][2][0];
        const int lo = lane * 4;

        // 12 conflict-free ds_read_b128 (lane*16B, wave covers 1KB/read)
        const float4 p0 = *(const float4*)(pb + lo);
        const float4 p1 = *(const float4*)(pb + lo + 256);
        const float4 p2 = *(const float4*)(pb + lo + 512);
        const float4 p3 = *(const float4*)(pb + lo + 768);
        const float4 t0 = *(const float4*)(tb + lo);
        const float4 t1 = *(const float4*)(tb + lo + 256);
        const float4 t2 = *(const float4*)(tb + lo + 512);
        const float4 t3 = *(const float4*)(tb + lo + 768);
        const float4 w0 = *(const float4*)(wb + lo);
        const float4 w1 = *(const float4*)(wb + lo + 256);
        const float4 w2 = *(const float4*)(wb + lo + 512);
        const float4 w3 = *(const float4*)(wb + lo + 768);

        unsigned nibs = 0;                    // byte q = correctness nibble
        CHUNK_FB(p0, t0, w0, 0)
        CHUNK_FB(p1, t1, w1, 1)
        CHUNK_FB(p2, t2, w2, 2)
        CHUNK_FB(p3, t3, w3, 3)

        // round-2 wave-private transpose: 1 dword write + 1 b128 read.
        // Lane's 16 bits cover elements [t*1024 + (lane>>4)*256 + (lane&15)*16, +16)
        nibbuf[wave * 64 + lane] = nibs;
        asm volatile("s_waitcnt lgkmcnt(0)" ::: "memory");
        const uint4 d = *(const uint4*)&nibbuf[wave * 64 + 4 * (lane & 15)];
        const int qs = (lane >> 4) * 8;       // chunk-selecting byte shift
        const unsigned mask = ((d.x >> qs) & 0xFu)
                            | (((d.y >> qs) & 0xFu) << 4)
                            | (((d.z >> qs) & 0xFu) << 8)
                            | (((d.w >> qs) & 0xFu) << 12);
        masks[t * 64 + (lane >> 4) * 16 + (lane & 15)] = (unsigned short)mask;
    }

    // one butterfly per wave for the whole kernel (amortized to ~0)
    #pragma unroll
    for (int off = 32; off; off >>= 1) sum += __shfl_down(sum, off);
    if (lane == 0) wv_wbce[wgid] = sum;
}

// ============================================================================
// Phase B: per-row max streak from masks. Row = 512B of bits; lane reads one
// aligned uint64 (64 contiguous elements), 64-bit doubling ladder, 6-step
// ordered shuffle combine. 256 blocks x 4 waves.
// ============================================================================
__global__ __launch_bounds__(256, 4) void phaseB_kernel(
        const unsigned short* __restrict__ masks,
        int* __restrict__ wv_streak, long rows) {
    const int lane = threadIdx.x & 63;
    const int wave = threadIdx.x >> 6;
    const long wgid = (long)blockIdx.x * 4 + wave;
    const long nwv  = (long)gridDim.x * 4;

    int acc = 0;
    for (long r = wgid; r < rows; r += nwv) {
        const unsigned long long m =
            *(const unsigned long long*)(masks + r * 256 + lane * 4);
        int pre, suf, mx;
        if (~m == 0ULL) {
            pre = suf = mx = 64;
        } else {
            pre = __builtin_ctzll(~m);            // leading-run (bit0 = first elem)
            suf = __builtin_clzll(~m);            // trailing-run (top bits)
            const unsigned long long pp1 = m;
            const unsigned long long pp2 = pp1 & (pp1 << 1);
            const unsigned long long pp4 = pp2 & (pp2 << 2);
            const unsigned long long pp8 = pp4 & (pp4 << 4);
            const unsigned long long pp16 = pp8 & (pp8 << 8);
            const unsigned long long pp32 = pp16 & (pp16 << 16);
            unsigned long long z; int len;
            if (pp32)      { z = pp32; len = 32; }
            else if (pp16) { z = pp16; len = 16; }
            else if (pp8)  { z = pp8;  len = 8; }
            else if (pp4)  { z = pp4;  len = 4; }
            else if (pp2)  { z = pp2;  len = 2; }
            else           { z = pp1;  len = 1; }
            { const unsigned long long q = (z << 16) & pp16; if (q) { z = q; len += 16; } }
            { const unsigned long long q = (z << 8)  & pp8;  if (q) { z = q; len += 8; } }
            { const unsigned long long q = (z << 4)  & pp4;  if (q) { z = q; len += 4; } }
            { const unsigned long long q = (z << 2)  & pp2;  if (q) { z = q; len += 2; } }
            { const unsigned long long q = (z << 1)  & pp1;  if (q) { z = q; len += 1; } }
            mx = m ? len : 0;
        }

        int alen = 64;
        #pragma unroll
        for (int off = 1; off < 64; off <<= 1) {
            const int bpre = __shfl_down(pre, off);
            const int bsuf = __shfl_down(suf, off);
            const int bmx  = __shfl_down(mx,  off);
            const int npre = (pre == alen) ? (alen + bpre) : pre;
            const int nsuf = (bsuf == alen) ? (alen + suf) : bsuf;
            mx  = max(max(mx, bmx), suf + bpre);
            pre = npre; suf = nsuf; alen <<= 1;
        }
        if (lane == 0) acc += mx;             // row max-streak
    }
    if (lane == 0) wv_streak[wgid] = acc;
}

// ============================================================================
// Finalize: sum 8192 wbce partials (double) + 1024 streak partials.
// ============================================================================
__global__ __launch_bounds__(1024) void finalize_kernel(
        const float* __restrict__ wv_wbce, int nA,
        const int* __restrict__ wv_streak, int nB,
        long long total_elems, float* __restrict__ out) {
    double s = 0.0;
    long long st = 0;
    for (int i = threadIdx.x; i < nA; i += 1024) s  += (double)wv_wbce[i];
    for (int i = threadIdx.x; i < nB; i += 1024) st += (long long)wv_streak[i];
    __shared__ double sd[1024];
    __shared__ long long sl[1024];
    sd[threadIdx.x] = s; sl[threadIdx.x] = st;
    __syncthreads();
    for (int o = 512; o; o >>= 1) {
        if (threadIdx.x < o) {
            sd[threadIdx.x] += sd[threadIdx.x + o];
            sl[threadIdx.x] += sl[threadIdx.x + o];
        }
        __syncthreads();
    }
    if (threadIdx.x == 0) {
        const double total = (double)total_elems;
        const double wbce = -LN2F * sd[0] / total;
        const double cwl  = 1.0 - (double)sl[0] / total;
        out[0] = (float)(0.5 * wbce + 0.5 * cwl);
    }
}

// ============================================================================
// Fallback (ws too small): round-0 proven single-pass kernel.
// ============================================================================
struct RunStats { int len, pre, suf, mx; };
__device__ inline RunStats rcombine(const RunStats& a, const RunStats& b) {
    RunStats r;
    r.len = a.len + b.len;
    r.pre = (a.pre == a.len) ? (a.len + b.pre) : a.pre;
    r.suf = (b.suf == b.len) ? (b.len + a.suf) : b.suf;
    r.mx  = max(max(a.mx, b.mx), a.suf + b.pre);
    return r;
}

__global__ __launch_bounds__(256) void fb_row_kernel(
        const float* __restrict__ yp, const float* __restrict__ yt,
        const float* __restrict__ dw,
        float* __restrict__ row_wbce, int* __restrict__ row_streak) {
    const int row  = blockIdx.x;
    const int lane = threadIdx.x & 63;
    const int wave = threadIdx.x >> 6;
    const long base = (long)row * 4096 + wave * 1024 + lane * 4;
    const float4* pp = (const float4*)(yp + base);
    const float4* tp = (const float4*)(yt + base);
    const float4* wp = (const float4*)(dw + base);

    float sum = 0.0f;
    unsigned nibs = 0;
    #pragma unroll
    for (int q = 0; q < 4; ++q) {
        const float4 P = pp[q * 64];
        const float4 T = tp[q * 64];
        const float4 W = wp[q * 64];
        CHUNK_FB(P, T, W, q)
    }
    __shared__ unsigned nibbuf[256];
    nibbuf[wave * 64 + lane] = nibs;
    __syncthreads();
    const uint4 d = *(const uint4*)&nibbuf[wave * 64 + 4 * (lane & 15)];
    const int qs = (lane >> 4) * 8;
    const unsigned mask = ((d.x >> qs) & 0xFu) | (((d.y >> qs) & 0xFu) << 4)
                        | (((d.z >> qs) & 0xFu) << 8) | (((d.w >> qs) & 0xFu) << 12);
    const int pre = __builtin_ctz(~mask);
    const int suf = __builtin_clz(~(mask << 16));
    int mx;
    {
        const unsigned p1 = mask, p2 = p1 & (p1 << 1), p4 = p2 & (p2 << 2), p8 = p4 & (p4 << 4);
        unsigned z; int len;
        if (p8) { z = p8; len = 8; } else if (p4) { z = p4; len = 4; }
        else if (p2) { z = p2; len = 2; } else { z = p1; len = 1; }
        { const unsigned q2 = (z << 8) & p8; if (q2) { z = q2; len += 8; } }
        { const unsigned q2 = (z << 4) & p4; if (q2) { z = q2; len += 4; } }
        { const unsigned q2 = (z << 2) & p2; if (q2) { z = q2; len += 2; } }
        { const unsigned q2 = (z << 1) & p1; if (q2) { z = q2; len += 1; } }
        mx = mask ? len : 0;
    }
    #pragma unroll
    for (int off = 32; off; off >>= 1) sum += __shfl_down(sum, off);
    int packed = pre | (suf << 10) | (mx << 20);
    int alen = 16;
    #pragma unroll
    for (int off = 1; off < 32; off <<= 1) {
        const int o = __shfl_down(packed, off);
        const int apre = packed & 1023, asuf = (packed >> 10) & 1023, amx = packed >> 20;
        const int bpre = o & 1023, bsuf = (o >> 10) & 1023, bmx = o >> 20;
        packed = ((apre == alen) ? (alen + bpre) : apre)
               | (((bsuf == alen) ? (alen + asuf) : bsuf) << 10)
               | (max(max(amx, bmx), asuf + bpre) << 20);
        alen <<= 1;
    }
    RunStats g;
    {
        const int o = __shfl_down(packed, 32);
        const int apre = packed & 1023, asuf = (packed >> 10) & 1023, amx = packed >> 20;
        const int bpre = o & 1023, bsuf = (o >> 10) & 1023, bmx = o >> 20;
        g.len = 1024;
        g.pre = (apre == 512) ? (512 + bpre) : apre;
        g.suf = (bsuf == 512) ? (512 + asuf) : bsuf;
        g.mx  = max(max(amx, bmx), asuf + bpre);
    }
    __shared__ RunStats sstat[4];
    __shared__ float ssum[4];
    if (lane == 0) { sstat[wave] = g; ssum[wave] = sum; }
    __syncthreads();
    if (threadIdx.x == 0) {
        RunStats r = rcombine(rcombine(sstat[0], sstat[1]), rcombine(sstat[2], sstat[3]));
        row_wbce[row]   = -LN2F * (ssum[0] + ssum[1] + ssum[2] + ssum[3]);
        row_streak[row] = r.mx;
    }
}

__global__ __launch_bounds__(1024) void fb_finalize_kernel(
        const float* __restrict__ row_wbce, const int* __restrict__ row_streak,
        int rows, float* __restrict__ out) {
    double s = 0.0; long long st = 0;
    for (int i = threadIdx.x; i < rows; i += 1024) {
        s += (double)row_wbce[i]; st += (long long)row_streak[i];
    }
    __shared__ double sd[1024];
    __shared__ long long sl[1024];
    sd[threadIdx.x] = s; sl[threadIdx.x] = st;
    __syncthreads();
    for (int o = 512; o; o >>= 1) {
        if (threadIdx.x < o) { sd[threadIdx.x] += sd[threadIdx.x + o]; sl[threadIdx.x] += sl[threadIdx.x + o]; }
        __syncthreads();
    }
    if (threadIdx.x == 0) {
        const double total = (double)rows * 4096.0;
        out[0] = (float)(0.5 * (sd[0] / total) + 0.5 * (1.0 - (double)sl[0] / total));
    }
}

extern "C" void kernel_launch(void* const* d_in, const int* in_sizes, int n_in,
                              void* d_out, int out_size, void* d_ws, size_t ws_size,
                              hipStream_t stream) {
    const float* yp = (const float*)d_in[0];
    const float* yt = (const float*)d_in[1];
    const float* dw = (const float*)d_in[2];
    float* out = (float*)d_out;

    const long rows = in_sizes[0] / 4096;             // 8192
    const long long total = (long long)rows * 4096;

    const size_t mask_bytes = (size_t)rows * 512;     // rows*256 ushorts = 4MB
    const size_t off_wbce   = mask_bytes;             // 8192 floats
    const size_t off_streak = off_wbce + 8192 * sizeof(float);
    const size_t need       = off_streak + 1024 * sizeof(int);

    if (ws_size >= need) {
        unsigned short* masks = (unsigned short*)d_ws;
        float* wv_wbce   = (float*)((char*)d_ws + off_wbce);
        int*   wv_streak = (int*)((char*)d_ws + off_streak);
        const long tiles_total = total / 1024;        // 1024-element tiles

        phaseA_kernel<<<4096, 128, 0, stream>>>(yp, yt, dw, masks, wv_wbce, tiles_total);
        phaseB_kernel<<<256, 256, 0, stream>>>(masks, wv_streak, rows);
        finalize_kernel<<<1, 1024, 0, stream>>>(wv_wbce, 8192, wv_streak, 1024, total, out);
    } else {
        float* row_wbce   = (float*)d_ws;
        int*   row_streak = (int*)((char*)d_ws + (size_t)rows * sizeof(float));
        fb_row_kernel<<<(int)rows, 256, 0, stream>>>(yp, yt, dw, row_wbce, row_streak);
        fb_finalize_kernel<<<1, 1024, 0, stream>>>(row_wbce, row_streak, (int)rows, out);
    }
}

// Round 7
// 348.039 us; speedup vs baseline: 1.0621x; 1.0398x over previous
//
#include <hip/hip_runtime.h>

#define EPS 1e-6f
#define LN2F 0.69314718055994530942f

struct RunStats { int len, pre, suf, mx; };

__device__ inline RunStats rcombine(const RunStats& a, const RunStats& b) {
    RunStats r;
    r.len = a.len + b.len;
    r.pre = (a.pre == a.len) ? (a.len + b.pre) : a.pre;
    r.suf = (b.suf == b.len) ? (b.len + a.suf) : b.suf;
    r.mx  = max(max(a.mx, b.mx), a.suf + b.pre);
    return r;
}

// One block (256 threads = 4 waves) per row of N=4096. Session verdict
// (rounds 0-6): this kernel runs at the chip's streaming-read ceiling
// (~5 B/cyc/CU = 3.1 TB/s delivered; 402MB irreducible input / 3.13 TB/s
// = 128.5us floor, measured 129us). Seven variants (row-pipelining,
// phase-split streaming, 24-deep register prefetch, asm-pinned loads,
// register-free global_load_lds staging with counted vmcnt) all pinned at
// 3.05-3.15 TB/s across occupancy 14-76% -> the wall is the per-CU read
// path, not concurrency, scratch, or the reduce tail (which hides entirely
// under the read wall here). The 2-launch structure is also ~12us cheaper
// than any 3-launch split. Do not split; do not add depth.
__global__ __launch_bounds__(256) void row_kernel(
        const float* __restrict__ yp, const float* __restrict__ yt,
        const float* __restrict__ dw,
        float* __restrict__ row_wbce, int* __restrict__ row_streak) {
    const int row  = blockIdx.x;
    const int lane = threadIdx.x & 63;
    const int wave = threadIdx.x >> 6;
    const long base = (long)row * 4096 + wave * 1024 + lane * 4;

    const float4* pp = (const float4*)(yp + base);
    const float4* tp = (const float4*)(yt + base);
    const float4* wp = (const float4*)(dw + base);

    // 12 independent coalesced loads.
    float4 P[4], T[4], W[4];
    #pragma unroll
    for (int q = 0; q < 4; ++q) {
        P[q] = pp[q * 64];   // +256 floats per chunk
        T[q] = tp[q * 64];
        W[q] = wp[q * 64];
    }

    float sum = 0.0f;        // accumulates w * log2(selected)
    unsigned nibs = 0;       // byte q = correctness nibble of chunk q
    #pragma unroll
    for (int q = 0; q < 4; ++q) {
        const float pv[4] = {P[q].x, P[q].y, P[q].z, P[q].w};
        const float tv[4] = {T[q].x, T[q].y, T[q].z, T[q].w};
        const float wv[4] = {W[q].x, W[q].y, W[q].z, W[q].w};
        #pragma unroll
        for (int c = 0; c < 4; ++c) {
            const bool tb = tv[c] != 0.0f;                   // y_true is 0/1
            const float sel = tb ? pv[c] : 1.0f - pv[c];
            sum = fmaf(wv[c], __log2f(sel + EPS), sum);
            const bool correct = (pv[c] > 0.5f) == tb;
            nibs |= (unsigned)correct << (8 * q + c);
        }
    }

    // ---- LDS nibble transpose: 1 dword write + 1 b128 broadcast read ----
    __shared__ unsigned nibbuf[256];           // 64 dwords per wave
    nibbuf[wave * 64 + lane] = nibs;
    __syncthreads();
    const uint4 d = *(const uint4*)&nibbuf[wave * 64 + 4 * (lane & 15)];
    const int qs = (lane >> 4) * 8;            // byte shift selecting chunk
    const unsigned mask = ((d.x >> qs) & 0xFu)
                        | (((d.y >> qs) & 0xFu) << 4)
                        | (((d.z >> qs) & 0xFu) << 8)
                        | (((d.w >> qs) & 0xFu) << 12);

    // ---- per-lane run stats over the 16-bit mask (bit0 = first element) ----
    const int pre = __builtin_ctz(~mask);            // 16 iff mask==0xffff
    const int suf = __builtin_clz(~(mask << 16));    // trailing-run via top bits
    int mx;
    {
        const unsigned p1 = mask;
        const unsigned p2 = p1 & (p1 << 1);   // bit i => run >= 2 ending at i
        const unsigned p4 = p2 & (p2 << 2);   // run >= 4
        const unsigned p8 = p4 & (p4 << 4);   // run >= 8
        unsigned z; int len;
        if (p8)      { z = p8; len = 8; }
        else if (p4) { z = p4; len = 4; }
        else if (p2) { z = p2; len = 2; }
        else         { z = p1; len = 1; }
        { const unsigned t = (z << 8) & p8; if (t) { z = t; len += 8; } }
        { const unsigned t = (z << 4) & p4; if (t) { z = t; len += 4; } }
        { const unsigned t = (z << 2) & p2; if (t) { z = t; len += 2; } }
        { const unsigned t = (z << 1) & p1; if (t) { z = t; len += 1; } }
        mx = mask ? len : 0;
    }

    // wbce wave sum (commutative butterfly)
    #pragma unroll
    for (int off = 32; off; off >>= 1) sum += __shfl_down(sum, off);

    // ordered wave reduce of (pre,suf,mx): 5 packed 10-bit steps (fields <=512),
    // then a final unpacked step (fields may reach 1024). Lane 0 valid.
    int packed = pre | (suf << 10) | (mx << 20);
    int alen = 16;
    #pragma unroll
    for (int off = 1; off < 32; off <<= 1) {
        const int o = __shfl_down(packed, off);
        const int apre = packed & 1023, asuf = (packed >> 10) & 1023, amx = packed >> 20;
        const int bpre = o & 1023,      bsuf = (o >> 10) & 1023,      bmx = o >> 20;
        const int npre = (apre == alen) ? (alen + bpre) : apre;
        const int nsuf = (bsuf == alen) ? (alen + asuf) : bsuf;
        const int nmx  = max(max(amx, bmx), asuf + bpre);
        packed = npre | (nsuf << 10) | (nmx << 20);
        alen <<= 1;
    }
    RunStats g;
    {   // final step: off = 32, alen = 512
        const int o = __shfl_down(packed, 32);
        const int apre = packed & 1023, asuf = (packed >> 10) & 1023, amx = packed >> 20;
        const int bpre = o & 1023,      bsuf = (o >> 10) & 1023,      bmx = o >> 20;
        g.len = 1024;
        g.pre = (apre == 512) ? (512 + bpre) : apre;
        g.suf = (bsuf == 512) ? (512 + asuf) : bsuf;
        g.mx  = max(max(amx, bmx), asuf + bpre);
    }

    __shared__ RunStats sstat[4];
    __shared__ float ssum[4];
    if (lane == 0) { sstat[wave] = g; ssum[wave] = sum; }
    __syncthreads();
    if (threadIdx.x == 0) {
        RunStats r = rcombine(rcombine(sstat[0], sstat[1]), rcombine(sstat[2], sstat[3]));
        row_wbce[row]   = -LN2F * (ssum[0] + ssum[1] + ssum[2] + ssum[3]);
        row_streak[row] = r.mx;
    }
}

__global__ __launch_bounds__(1024) void finalize_kernel(
        const float* __restrict__ row_wbce, const int* __restrict__ row_streak,
        int rows, float* __restrict__ out) {
    double s = 0.0;
    long long st = 0;
    for (int i = threadIdx.x; i < rows; i += 1024) {
        s  += (double)row_wbce[i];
        st += (long long)row_streak[i];
    }
    __shared__ double sd[1024];
    __shared__ long long sl[1024];
    sd[threadIdx.x] = s; sl[threadIdx.x] = st;
    __syncthreads();
    for (int o = 512; o; o >>= 1) {
        if (threadIdx.x < o) {
            sd[threadIdx.x] += sd[threadIdx.x + o];
            sl[threadIdx.x] += sl[threadIdx.x + o];
        }
        __syncthreads();
    }
    if (threadIdx.x == 0) {
        const double total = (double)rows * 4096.0;
        const double wbce = sd[0] / total;
        const double cwl  = 1.0 - (double)sl[0] / total;
        out[0] = (float)(0.5 * wbce + 0.5 * cwl);
    }
}

extern "C" void kernel_launch(void* const* d_in, const int* in_sizes, int n_in,
                              void* d_out, int out_size, void* d_ws, size_t ws_size,
                              hipStream_t stream) {
    const float* yp = (const float*)d_in[0];
    const float* yt = (const float*)d_in[1];
    const float* dw = (const float*)d_in[2];
    float* out = (float*)d_out;

    const int rows = in_sizes[0] / 4096;   // 8192
    float* row_wbce   = (float*)d_ws;
    int*   row_streak = (int*)((char*)d_ws + (size_t)rows * sizeof(float));

    row_kernel<<<rows, 256, 0, stream>>>(yp, yt, dw, row_wbce, row_streak);
    finalize_kernel<<<1, 1024, 0, stream>>>(row_wbce, row_streak, rows, out);
}